// Round 9
// baseline (369.010 us; speedup 1.0000x reference)
//
#include <hip/hip_runtime.h>
#include <hip/hip_bf16.h>

typedef __attribute__((ext_vector_type(8))) short bf16x8;
typedef __attribute__((ext_vector_type(4))) float floatx4;

constexpr int D_MODEL = 2048;
constexpr int N_HEADS = 32;
constexpr int N_KV    = 8;
constexpr int B_      = 2;
constexpr int T_      = 2048;
constexpr int BT      = B_ * T_;        // 4096
constexpr int NQKV    = 3072;           // 2048 Q + 512 K + 512 V

// Q pre-scale: 1/sqrt(64) * log2(e), folded into QKV-GEMM epilogue so the
// attention inner loop is a bare v_exp (p = 2^s).
constexpr float Q_SCALE = 0.18033688011112042f;

__device__ __forceinline__ unsigned short f2bf(float f) {
    __hip_bfloat16 h = __float2bfloat16(f);
    return *reinterpret_cast<unsigned short*>(&h);
}

// async 16B global->LDS; lds base wave-uniform, lane i lands at base + i*16.
__device__ __forceinline__ void gll16(const void* g, void* l) {
    typedef const __attribute__((address_space(1))) unsigned int* gp_t;
    typedef __attribute__((address_space(3))) unsigned int* lp_t;
    __builtin_amdgcn_global_load_lds((gp_t)g, (lp_t)l, 16, 0, 0);
}

// fused f32->bf16 of [x | Wq | Wk | Wv] into contiguous dst
__global__ __launch_bounds__(256) void cvt_all(
        const float* __restrict__ x,  const float* __restrict__ wq,
        const float* __restrict__ wk, const float* __restrict__ wv,
        unsigned short* __restrict__ dst) {
    size_t i4 = (size_t)blockIdx.x * 256 + threadIdx.x;
    size_t e = i4 * 4;
    const float* src; size_t off;
    if (e < 8388608)        { src = x;  off = 0; }
    else if (e < 12582912)  { src = wq; off = 8388608; }
    else if (e < 13631488)  { src = wk; off = 12582912; }
    else                    { src = wv; off = 13631488; }
    float4 f = *reinterpret_cast<const float4*>(src + (e - off));
    unsigned short u[4] = {f2bf(f.x), f2bf(f.y), f2bf(f.z), f2bf(f.w)};
    reinterpret_cast<uint2*>(dst)[i4] = *reinterpret_cast<const uint2*>(u);
}

__global__ __launch_bounds__(256) void cvt_bf16(
        const float* __restrict__ src, unsigned short* __restrict__ dst, int n4) {
    int i = blockIdx.x * 256 + threadIdx.x;
    if (i < n4) {
        float4 f = reinterpret_cast<const float4*>(src)[i];
        unsigned short u[4] = {f2bf(f.x), f2bf(f.y), f2bf(f.z), f2bf(f.w)};
        reinterpret_cast<uint2*>(dst)[i] = *reinterpret_cast<const uint2*>(u);
    }
}

// C[M,N] = A[M,K] @ B[N,K]^T, bf16 in, 128x128 tile, BK=64, XOR-swizzled LDS.
template<bool C_F32, bool SCALEQ>
__global__ __launch_bounds__(256) void gemm128(
        const unsigned short* __restrict__ A,
        const unsigned short* __restrict__ Bb,
        void* __restrict__ Cp,
        int M, int N, int K) {
    __shared__ unsigned short As[128 * 64];
    __shared__ unsigned short Bs[128 * 64];
    const int t = threadIdx.x;
    const int wave = t >> 6, lane = t & 63;
    const int l16 = lane & 15, quad = lane >> 4;
    const int wm = (wave & 1) * 64, wn = (wave >> 1) * 64;
    const int mtile = blockIdx.y * 128, ntile = blockIdx.x * 128;

    floatx4 acc[4][4] = {};

    for (int k0 = 0; k0 < K; k0 += 64) {
        __syncthreads();
#pragma unroll
        for (int c = 0; c < 4; c++) {
            int s = (c * 4 + wave) * 64 + lane;
            int row = s >> 3, k8 = (s & 7) ^ (row & 7);
            gll16(&A[(size_t)(mtile + row) * K + k0 + k8 * 8], &As[(c * 4 + wave) * 512]);
            gll16(&Bb[(size_t)(ntile + row) * K + k0 + k8 * 8], &Bs[(c * 4 + wave) * 512]);
        }
        __syncthreads();
#pragma unroll
        for (int kc = 0; kc < 2; kc++) {
            bf16x8 af[4], bfr[4];
#pragma unroll
            for (int i = 0; i < 4; i++) {
                int arow = wm + i * 16 + l16;
                af[i] = *reinterpret_cast<const bf16x8*>(
                    &As[(arow * 8 + ((kc * 4 + quad) ^ (arow & 7))) * 8]);
                int brow = wn + i * 16 + l16;
                bfr[i] = *reinterpret_cast<const bf16x8*>(
                    &Bs[(brow * 8 + ((kc * 4 + quad) ^ (brow & 7))) * 8]);
            }
#pragma unroll
            for (int i = 0; i < 4; i++)
#pragma unroll
                for (int jn = 0; jn < 4; jn++)
                    acc[i][jn] = __builtin_amdgcn_mfma_f32_16x16x32_bf16(
                        af[i], bfr[jn], acc[i][jn], 0, 0, 0);
        }
    }
    float cscale = (SCALEQ && ntile < 2048) ? Q_SCALE : 1.0f;
#pragma unroll
    for (int i = 0; i < 4; i++)
#pragma unroll
        for (int jn = 0; jn < 4; jn++)
#pragma unroll
            for (int r = 0; r < 4; r++) {
                int row = mtile + wm + i * 16 + quad * 4 + r;
                int col = ntile + wn + jn * 16 + l16;
                if constexpr (C_F32)
                    ((float*)Cp)[(size_t)row * N + col] = acc[i][jn][r];
                else
                    ((unsigned short*)Cp)[(size_t)row * N + col] =
                        f2bf(acc[i][jn][r] * cscale);
            }
}

// V columns of QKV -> Vt[bg][dim 64][token 2048]
__global__ __launch_bounds__(256) void vtrans(
        const unsigned short* __restrict__ QKV,
        unsigned short* __restrict__ Vt) {
    __shared__ unsigned short Ts[64][72];
    const int tb = blockIdx.x * 64;
    const int bg = blockIdx.y;
    const int b = bg >> 3, g = bg & 7;
    const int t = threadIdx.x;
#pragma unroll
    for (int it = 0; it < 2; it++) {
        int row = (t >> 3) + it * 32;
        int sl = t & 7;
        *reinterpret_cast<uint4*>(&Ts[row][sl * 8]) =
            *reinterpret_cast<const uint4*>(
                &QKV[(size_t)(b * T_ + tb + row) * NQKV + 2560 + g * 64 + sl * 8]);
    }
    __syncthreads();
#pragma unroll
    for (int it = 0; it < 2; it++) {
        int d = (t >> 3) + it * 32;
        int ks = t & 7;
        unsigned short u[8];
#pragma unroll
        for (int j = 0; j < 8; j++) u[j] = Ts[ks * 8 + j][d];
        *reinterpret_cast<uint4*>(&Vt[((size_t)bg * 64 + d) * T_ + tb + ks * 8]) =
            *reinterpret_cast<const uint4*>(u);
    }
}

// Flash causal GQA with GQA-group sharing: block = one 64-q tile x ALL 4 heads
// of kv-group g; wave w handles head g*4+w for all 64 q rows. Staged K/V tile
// feeds 4 heads (staging /4) and each wave's K/V LDS reads amortize over 64 q.
// grid (32, B*N_KV); qtl = 31 - blockIdx.x (longest first; all 512 resident).
__global__ __launch_bounds__(256) void attn8(
        const unsigned short* __restrict__ QKV,   // [4096][3072]
        const unsigned short* __restrict__ Vt,    // [16*64][2048]
        unsigned short* __restrict__ O) {         // [4096][2048]
    __shared__ unsigned short Ks[64 * 64];        // swizzled [key][dim]
    __shared__ unsigned short Vs[64 * 64];        // swizzled [dim][key]
    __shared__ unsigned short Ps[4][64 * 72];     // per-wave P, [q(64)][key 64]
    const int qt = 31 - blockIdx.x;               // q-tile index (64 rows)
    const int bg = blockIdx.y;
    const int b = bg >> 3, g = bg & 7;
    const int t = threadIdx.x, wave = t >> 6, lane = t & 63;
    const int l16 = lane & 15, quad = lane >> 4;
    const int h = g * 4 + wave;                   // this wave's head

    bf16x8 ones;
#pragma unroll
    for (int i = 0; i < 8; i++) ones[i] = (short)0x3F80;   // bf16 1.0

    const int qlo = qt * 64;

    bf16x8 qf[4][2];
#pragma unroll
    for (int qb = 0; qb < 4; qb++) {
        const unsigned short* qptr =
            QKV + (size_t)(b * T_ + qlo + qb * 16 + l16) * NQKV + h * 64;
        qf[qb][0] = *reinterpret_cast<const bf16x8*>(qptr + quad * 8);
        qf[qb][1] = *reinterpret_cast<const bf16x8*>(qptr + 32 + quad * 8);
    }

    floatx4 o[4][4] = {};     // [qb][dt]
    floatx4 lacc[4] = {};

    for (int kt = 0; kt <= qt; kt++) {
        const int kb = kt * 64;
        __syncthreads();
#pragma unroll
        for (int c = 0; c < 2; c++) {
            int s = (c * 4 + wave) * 64 + lane;
            int row = s >> 3, k8 = (s & 7) ^ (row & 7);
            gll16(&QKV[(size_t)(b * T_ + kb + row) * NQKV + 2048 + g * 64 + k8 * 8],
                  &Ks[(c * 4 + wave) * 512]);
            gll16(&Vt[((size_t)bg * 64 + row) * T_ + kb + k8 * 8],
                  &Vs[(c * 4 + wave) * 512]);
        }
        __syncthreads();

        const bool diag = (kt == qt);

        // S^T per 16-key row-block; exp; pack into per-wave Ps
#pragma unroll
        for (int km = 0; km < 4; km++) {
            int krow = km * 16 + l16;
            bf16x8 k0 = *reinterpret_cast<const bf16x8*>(
                &Ks[(krow * 8 + (quad ^ (krow & 7))) * 8]);
            bf16x8 k1 = *reinterpret_cast<const bf16x8*>(
                &Ks[(krow * 8 + ((4 + quad) ^ (krow & 7))) * 8]);
#pragma unroll
            for (int qb = 0; qb < 4; qb++) {
                floatx4 z = {};
                z = __builtin_amdgcn_mfma_f32_16x16x32_bf16(k0, qf[qb][0], z, 0, 0, 0);
                z = __builtin_amdgcn_mfma_f32_16x16x32_bf16(k1, qf[qb][1], z, 0, 0, 0);
                unsigned short u[4];
                if (diag) {
                    int qq = qlo + qb * 16 + l16;
#pragma unroll
                    for (int r = 0; r < 4; r++) {
                        float p = __builtin_amdgcn_exp2f(z[r]);
                        if ((kb + km * 16 + quad * 4 + r) > qq) p = 0.f;
                        u[r] = f2bf(p);
                    }
                } else {
#pragma unroll
                    for (int r = 0; r < 4; r++)
                        u[r] = f2bf(__builtin_amdgcn_exp2f(z[r]));
                }
                *reinterpret_cast<uint2*>(
                    &Ps[wave][(qb * 16 + l16) * 72 + km * 16 + quad * 4]) =
                    *reinterpret_cast<const uint2*>(u);
            }
        }

        // P fragments (A-layout), l-sum via MFMA, then PV
        bf16x8 pf[4][2];
#pragma unroll
        for (int qb = 0; qb < 4; qb++) {
#pragma unroll
            for (int ks = 0; ks < 2; ks++)
                pf[qb][ks] = *reinterpret_cast<const bf16x8*>(
                    &Ps[wave][(qb * 16 + l16) * 72 + ks * 32 + quad * 8]);
            lacc[qb] = __builtin_amdgcn_mfma_f32_16x16x32_bf16(
                pf[qb][0], ones, lacc[qb], 0, 0, 0);
            lacc[qb] = __builtin_amdgcn_mfma_f32_16x16x32_bf16(
                pf[qb][1], ones, lacc[qb], 0, 0, 0);
        }
#pragma unroll
        for (int dt = 0; dt < 4; dt++) {
            int vrow = dt * 16 + l16;
            bf16x8 v0 = *reinterpret_cast<const bf16x8*>(
                &Vs[(vrow * 8 + (quad ^ (vrow & 7))) * 8]);
            bf16x8 v1 = *reinterpret_cast<const bf16x8*>(
                &Vs[(vrow * 8 + ((4 + quad) ^ (vrow & 7))) * 8]);
#pragma unroll
            for (int qb = 0; qb < 4; qb++) {
                o[qb][dt] = __builtin_amdgcn_mfma_f32_16x16x32_bf16(
                    pf[qb][0], v0, o[qb][dt], 0, 0, 0);
                o[qb][dt] = __builtin_amdgcn_mfma_f32_16x16x32_bf16(
                    pf[qb][1], v1, o[qb][dt], 0, 0, 0);
            }
        }
    }

    // epilogue
#pragma unroll
    for (int qb = 0; qb < 4; qb++)
#pragma unroll
        for (int r = 0; r < 4; r++) {
            float inv = 1.0f / lacc[qb][r];
            int row = b * T_ + qlo + qb * 16 + quad * 4 + r;
#pragma unroll
            for (int dt = 0; dt < 4; dt++)
                O[(size_t)row * D_MODEL + h * 64 + dt * 16 + l16] =
                    f2bf(o[qb][dt][r] * inv);
        }
}

extern "C" void kernel_launch(void* const* d_in, const int* in_sizes, int n_in,
                              void* d_out, int out_size, void* d_ws, size_t ws_size,
                              hipStream_t stream) {
    const float* x  = (const float*)d_in[0];
    const float* Wq = (const float*)d_in[1];
    const float* Wk = (const float*)d_in[2];
    const float* Wv = (const float*)d_in[3];
    const float* Wo = (const float*)d_in[4];

    unsigned short* xb   = (unsigned short*)d_ws;             // [4096][2048]
    unsigned short* Wqkv = xb + (size_t)BT * D_MODEL;         // [3072][2048]
    unsigned short* QKVo = Wqkv + (size_t)NQKV * D_MODEL;     // [4096][3072]
    unsigned short* Vt   = QKVo + (size_t)BT * NQKV;          // [16][64][2048]
    unsigned short* Aw   = xb;                                 // reuse after QKV GEMM
    unsigned short* Wob  = Wqkv;                               // reuse after QKV GEMM

    dim3 blk(256);
    cvt_all<<<dim3(14336), blk, 0, stream>>>(x, Wq, Wk, Wv, xb);
    // fused QKV projection; Q columns pre-scaled by 1/8*log2(e)
    gemm128<false, true><<<dim3(NQKV / 128, BT / 128), blk, 0, stream>>>(
        xb, Wqkv, QKVo, BT, NQKV, D_MODEL);
    cvt_bf16<<<dim3(D_MODEL * D_MODEL / 4 / 256), blk, 0, stream>>>(
        Wo, Wob, D_MODEL * D_MODEL / 4);
    vtrans<<<dim3(T_ / 64, B_ * N_KV), blk, 0, stream>>>(QKVo, Vt);
    attn8<<<dim3(32, B_ * N_KV), blk, 0, stream>>>(QKVo, Vt, Aw);
    gemm128<true, false><<<dim3(D_MODEL / 128, BT / 128), blk, 0, stream>>>(
        Aw, Wob, d_out, BT, D_MODEL, D_MODEL);
}

// Round 10
// 279.657 us; speedup vs baseline: 1.3195x; 1.3195x over previous
//
#include <hip/hip_runtime.h>
#include <hip/hip_bf16.h>

typedef __attribute__((ext_vector_type(8))) short bf16x8;
typedef __attribute__((ext_vector_type(4))) float floatx4;

constexpr int D_MODEL = 2048;
constexpr int N_HEADS = 32;
constexpr int N_KV    = 8;
constexpr int B_      = 2;
constexpr int T_      = 2048;
constexpr int BT      = B_ * T_;        // 4096
constexpr int NQKV    = 3072;           // 2048 Q + 512 K + 512 V

// Q pre-scale: 1/sqrt(64) * log2(e), folded into QKV-GEMM epilogue so the
// attention inner loop is a bare v_exp (p = 2^s).
constexpr float Q_SCALE = 0.18033688011112042f;

__device__ __forceinline__ unsigned short f2bf(float f) {
    __hip_bfloat16 h = __float2bfloat16(f);
    return *reinterpret_cast<unsigned short*>(&h);
}

// async 16B global->LDS; lds base wave-uniform, lane i lands at base + i*16.
__device__ __forceinline__ void gll16(const void* g, void* l) {
    typedef const __attribute__((address_space(1))) unsigned int* gp_t;
    typedef __attribute__((address_space(3))) unsigned int* lp_t;
    __builtin_amdgcn_global_load_lds((gp_t)g, (lp_t)l, 16, 0, 0);
}

// fused f32->bf16 of [x | Wq | Wk | Wv] into contiguous dst
__global__ __launch_bounds__(256) void cvt_all(
        const float* __restrict__ x,  const float* __restrict__ wq,
        const float* __restrict__ wk, const float* __restrict__ wv,
        unsigned short* __restrict__ dst) {
    size_t i4 = (size_t)blockIdx.x * 256 + threadIdx.x;
    size_t e = i4 * 4;
    const float* src; size_t off;
    if (e < 8388608)        { src = x;  off = 0; }
    else if (e < 12582912)  { src = wq; off = 8388608; }
    else if (e < 13631488)  { src = wk; off = 12582912; }
    else                    { src = wv; off = 13631488; }
    float4 f = *reinterpret_cast<const float4*>(src + (e - off));
    unsigned short u[4] = {f2bf(f.x), f2bf(f.y), f2bf(f.z), f2bf(f.w)};
    reinterpret_cast<uint2*>(dst)[i4] = *reinterpret_cast<const uint2*>(u);
}

__global__ __launch_bounds__(256) void cvt_bf16(
        const float* __restrict__ src, unsigned short* __restrict__ dst, int n4) {
    int i = blockIdx.x * 256 + threadIdx.x;
    if (i < n4) {
        float4 f = reinterpret_cast<const float4*>(src)[i];
        unsigned short u[4] = {f2bf(f.x), f2bf(f.y), f2bf(f.z), f2bf(f.w)};
        reinterpret_cast<uint2*>(dst)[i] = *reinterpret_cast<const uint2*>(u);
    }
}

// C[M,N] = A[M,K] @ B[N,K]^T, bf16 in, 128x128 tile, BK=64, XOR-swizzled LDS.
template<bool C_F32, bool SCALEQ>
__global__ __launch_bounds__(256) void gemm128(
        const unsigned short* __restrict__ A,
        const unsigned short* __restrict__ Bb,
        void* __restrict__ Cp,
        int M, int N, int K) {
    __shared__ unsigned short As[128 * 64];
    __shared__ unsigned short Bs[128 * 64];
    const int t = threadIdx.x;
    const int wave = t >> 6, lane = t & 63;
    const int l16 = lane & 15, quad = lane >> 4;
    const int wm = (wave & 1) * 64, wn = (wave >> 1) * 64;
    const int mtile = blockIdx.y * 128, ntile = blockIdx.x * 128;

    floatx4 acc[4][4] = {};

    for (int k0 = 0; k0 < K; k0 += 64) {
        __syncthreads();
#pragma unroll
        for (int c = 0; c < 4; c++) {
            int s = (c * 4 + wave) * 64 + lane;
            int row = s >> 3, k8 = (s & 7) ^ (row & 7);
            gll16(&A[(size_t)(mtile + row) * K + k0 + k8 * 8], &As[(c * 4 + wave) * 512]);
            gll16(&Bb[(size_t)(ntile + row) * K + k0 + k8 * 8], &Bs[(c * 4 + wave) * 512]);
        }
        __syncthreads();
#pragma unroll
        for (int kc = 0; kc < 2; kc++) {
            bf16x8 af[4], bfr[4];
#pragma unroll
            for (int i = 0; i < 4; i++) {
                int arow = wm + i * 16 + l16;
                af[i] = *reinterpret_cast<const bf16x8*>(
                    &As[(arow * 8 + ((kc * 4 + quad) ^ (arow & 7))) * 8]);
                int brow = wn + i * 16 + l16;
                bfr[i] = *reinterpret_cast<const bf16x8*>(
                    &Bs[(brow * 8 + ((kc * 4 + quad) ^ (brow & 7))) * 8]);
            }
#pragma unroll
            for (int i = 0; i < 4; i++)
#pragma unroll
                for (int jn = 0; jn < 4; jn++)
                    acc[i][jn] = __builtin_amdgcn_mfma_f32_16x16x32_bf16(
                        af[i], bfr[jn], acc[i][jn], 0, 0, 0);
        }
    }
    float cscale = (SCALEQ && ntile < 2048) ? Q_SCALE : 1.0f;
#pragma unroll
    for (int i = 0; i < 4; i++)
#pragma unroll
        for (int jn = 0; jn < 4; jn++)
#pragma unroll
            for (int r = 0; r < 4; r++) {
                int row = mtile + wm + i * 16 + quad * 4 + r;
                int col = ntile + wn + jn * 16 + l16;
                if constexpr (C_F32)
                    ((float*)Cp)[(size_t)row * N + col] = acc[i][jn][r];
                else
                    ((unsigned short*)Cp)[(size_t)row * N + col] =
                        f2bf(acc[i][jn][r] * cscale);
            }
}

// V columns of QKV -> Vt[bg][dim 64][token 2048]
__global__ __launch_bounds__(256) void vtrans(
        const unsigned short* __restrict__ QKV,
        unsigned short* __restrict__ Vt) {
    __shared__ unsigned short Ts[64][72];
    const int tb = blockIdx.x * 64;
    const int bg = blockIdx.y;
    const int b = bg >> 3, g = bg & 7;
    const int t = threadIdx.x;
#pragma unroll
    for (int it = 0; it < 2; it++) {
        int row = (t >> 3) + it * 32;
        int sl = t & 7;
        *reinterpret_cast<uint4*>(&Ts[row][sl * 8]) =
            *reinterpret_cast<const uint4*>(
                &QKV[(size_t)(b * T_ + tb + row) * NQKV + 2560 + g * 64 + sl * 8]);
    }
    __syncthreads();
#pragma unroll
    for (int it = 0; it < 2; it++) {
        int d = (t >> 3) + it * 32;
        int ks = t & 7;
        unsigned short u[8];
#pragma unroll
        for (int j = 0; j < 8; j++) u[j] = Ts[ks * 8 + j][d];
        *reinterpret_cast<uint4*>(&Vt[((size_t)bg * 64 + d) * T_ + tb + ks * 8]) =
            *reinterpret_cast<const uint4*>(u);
    }
}

// Flash causal GQA. 128-q tiles, 32 q-rows PER WAVE (K/V fragment reads reused
// across two 16-q sub-blocks). grid (8, B*NH); block does 128-q tiles j and
// 15-j sequentially -> uniform 34 key-tiles per block (load-balance optimal).
__global__ __launch_bounds__(256, 2) void attn5(
        const unsigned short* __restrict__ QKV,   // [4096][3072]
        const unsigned short* __restrict__ Vt,    // [16*64][2048]
        unsigned short* __restrict__ O) {         // [4096][2048]
    __shared__ unsigned short Ks[64 * 64];        // swizzled [key][dim]
    __shared__ unsigned short Vs[64 * 64];        // swizzled [dim][key]
    __shared__ unsigned short Ps[4][32 * 72];     // per-wave P, [q(32)][key 64]
    const int j  = blockIdx.x;
    const int bh = blockIdx.y;
    const int b = bh >> 5, h = bh & 31;
    const int g = h >> 2;
    const int t = threadIdx.x, wave = t >> 6, lane = t & 63;
    const int l16 = lane & 15, quad = lane >> 4;

    bf16x8 ones;
#pragma unroll
    for (int i = 0; i < 8; i++) ones[i] = (short)0x3F80;   // bf16 1.0

    for (int pp = 0; pp < 2; pp++) {
        const int qtl = pp ? (15 - j) : j;
        const int q0  = qtl * 128;
        const int qlo = q0 + wave * 32;           // this wave's first q row

        bf16x8 qf[2][2];
#pragma unroll
        for (int qb = 0; qb < 2; qb++) {
            const unsigned short* qptr =
                QKV + (size_t)(b * T_ + qlo + qb * 16 + l16) * NQKV + h * 64;
            qf[qb][0] = *reinterpret_cast<const bf16x8*>(qptr + quad * 8);
            qf[qb][1] = *reinterpret_cast<const bf16x8*>(qptr + 32 + quad * 8);
        }

        floatx4 o[2][4] = {};
        floatx4 lacc[2] = {};

        const int nkt = 2 * qtl + 2;
        for (int kt = 0; kt < nkt; kt++) {
            const int kb = kt * 64;
            __syncthreads();
#pragma unroll
            for (int c = 0; c < 2; c++) {
                int s = (c * 4 + wave) * 64 + lane;
                int row = s >> 3, k8 = (s & 7) ^ (row & 7);
                gll16(&QKV[(size_t)(b * T_ + kb + row) * NQKV + 2048 + g * 64 + k8 * 8],
                      &Ks[(c * 4 + wave) * 512]);
                gll16(&Vt[((size_t)(b * 8 + g) * 64 + row) * T_ + kb + k8 * 8],
                      &Vs[(c * 4 + wave) * 512]);
            }
            __syncthreads();

            if (kb > qlo + 31) continue;          // no visible keys for this wave
            const bool needmask = (kb + 63 > qlo);

            // S^T per 16-key row-block; exp; pack into Ps
#pragma unroll
            for (int km = 0; km < 4; km++) {
                int krow = km * 16 + l16;
                bf16x8 k0 = *reinterpret_cast<const bf16x8*>(
                    &Ks[(krow * 8 + (quad ^ (krow & 7))) * 8]);
                bf16x8 k1 = *reinterpret_cast<const bf16x8*>(
                    &Ks[(krow * 8 + ((4 + quad) ^ (krow & 7))) * 8]);
#pragma unroll
                for (int qb = 0; qb < 2; qb++) {
                    floatx4 z = {};
                    z = __builtin_amdgcn_mfma_f32_16x16x32_bf16(k0, qf[qb][0], z, 0, 0, 0);
                    z = __builtin_amdgcn_mfma_f32_16x16x32_bf16(k1, qf[qb][1], z, 0, 0, 0);
                    unsigned short u[4];
                    if (needmask) {
                        int qq = qlo + qb * 16 + l16;
#pragma unroll
                        for (int r = 0; r < 4; r++) {
                            float p = __builtin_amdgcn_exp2f(z[r]);
                            if ((kb + km * 16 + quad * 4 + r) > qq) p = 0.f;
                            u[r] = f2bf(p);
                        }
                    } else {
#pragma unroll
                        for (int r = 0; r < 4; r++)
                            u[r] = f2bf(__builtin_amdgcn_exp2f(z[r]));
                    }
                    *reinterpret_cast<uint2*>(
                        &Ps[wave][(qb * 16 + l16) * 72 + km * 16 + quad * 4]) =
                        *reinterpret_cast<const uint2*>(u);
                }
            }

            // P fragments (A-layout), l-sum via MFMA, then PV
            bf16x8 pf[2][2];
#pragma unroll
            for (int qb = 0; qb < 2; qb++) {
#pragma unroll
                for (int ks = 0; ks < 2; ks++)
                    pf[qb][ks] = *reinterpret_cast<const bf16x8*>(
                        &Ps[wave][(qb * 16 + l16) * 72 + ks * 32 + quad * 8]);
                lacc[qb] = __builtin_amdgcn_mfma_f32_16x16x32_bf16(
                    pf[qb][0], ones, lacc[qb], 0, 0, 0);
                lacc[qb] = __builtin_amdgcn_mfma_f32_16x16x32_bf16(
                    pf[qb][1], ones, lacc[qb], 0, 0, 0);
            }
#pragma unroll
            for (int dt = 0; dt < 4; dt++) {
                int vrow = dt * 16 + l16;
                bf16x8 v0 = *reinterpret_cast<const bf16x8*>(
                    &Vs[(vrow * 8 + (quad ^ (vrow & 7))) * 8]);
                bf16x8 v1 = *reinterpret_cast<const bf16x8*>(
                    &Vs[(vrow * 8 + ((4 + quad) ^ (vrow & 7))) * 8]);
#pragma unroll
                for (int qb = 0; qb < 2; qb++) {
                    o[qb][dt] = __builtin_amdgcn_mfma_f32_16x16x32_bf16(
                        pf[qb][0], v0, o[qb][dt], 0, 0, 0);
                    o[qb][dt] = __builtin_amdgcn_mfma_f32_16x16x32_bf16(
                        pf[qb][1], v1, o[qb][dt], 0, 0, 0);
                }
            }
        }

        // epilogue
#pragma unroll
        for (int qb = 0; qb < 2; qb++)
#pragma unroll
            for (int r = 0; r < 4; r++) {
                float inv = 1.0f / lacc[qb][r];
                int row = b * T_ + qlo + qb * 16 + quad * 4 + r;
#pragma unroll
                for (int dt = 0; dt < 4; dt++)
                    O[(size_t)row * D_MODEL + h * 64 + dt * 16 + l16] =
                        f2bf(o[qb][dt][r] * inv);
            }
    }
}

extern "C" void kernel_launch(void* const* d_in, const int* in_sizes, int n_in,
                              void* d_out, int out_size, void* d_ws, size_t ws_size,
                              hipStream_t stream) {
    const float* x  = (const float*)d_in[0];
    const float* Wq = (const float*)d_in[1];
    const float* Wk = (const float*)d_in[2];
    const float* Wv = (const float*)d_in[3];
    const float* Wo = (const float*)d_in[4];

    unsigned short* xb   = (unsigned short*)d_ws;             // [4096][2048]
    unsigned short* Wqkv = xb + (size_t)BT * D_MODEL;         // [3072][2048]
    unsigned short* QKVo = Wqkv + (size_t)NQKV * D_MODEL;     // [4096][3072]
    unsigned short* Vt   = QKVo + (size_t)BT * NQKV;          // [16][64][2048]
    unsigned short* Aw   = xb;                                 // reuse after QKV GEMM
    unsigned short* Wob  = Wqkv;                               // reuse after QKV GEMM

    dim3 blk(256);
    cvt_all<<<dim3(14336), blk, 0, stream>>>(x, Wq, Wk, Wv, xb);
    // fused QKV projection; Q columns pre-scaled by 1/8*log2(e)
    gemm128<false, true><<<dim3(NQKV / 128, BT / 128), blk, 0, stream>>>(
        xb, Wqkv, QKVo, BT, NQKV, D_MODEL);
    cvt_bf16<<<dim3(D_MODEL * D_MODEL / 4 / 256), blk, 0, stream>>>(
        Wo, Wob, D_MODEL * D_MODEL / 4);
    vtrans<<<dim3(T_ / 64, B_ * N_KV), blk, 0, stream>>>(QKVo, Vt);
    attn5<<<dim3(8, B_ * N_HEADS), blk, 0, stream>>>(QKVo, Vt, Aw);
    gemm128<true, false><<<dim3(D_MODEL / 128, BT / 128), blk, 0, stream>>>(
        Aw, Wob, d_out, BT, D_MODEL, D_MODEL);
}